// Round 11
// baseline (430.424 us; speedup 1.0000x reference)
//
#include <hip/hip_runtime.h>
#include <hip/hip_bf16.h>
#include <float.h>

typedef _Float16 f16x8 __attribute__((ext_vector_type(8)));
typedef float f32x4 __attribute__((ext_vector_type(4)));

#define GRAPHS 64
#define NPG 2048
#define DIM 128
#define NNODES (GRAPHS * NPG)
#define NEDGES (NNODES * 16)
#define ECAP 32768   // edges per graph
#define NSB 8        // sub-blocks per graph for CSR build
#define RSLICES 16
#define RPB 256      // rows per block in sage_gemm

// ---------------- embed: xh[i] = (f16) emb[node_ids[i]] ----------------
__global__ __launch_bounds__(256) void embed_kernel(const int* __restrict__ ids,
    const float* __restrict__ emb, _Float16* __restrict__ xh) {
  int idx = blockIdx.x * 256 + threadIdx.x;
  int nd = idx >> 4, part = idx & 15;
  int id = ids[nd];
  const float* src = emb + (size_t)id * 128 + part * 8;
  float4 a = *(const float4*)(src);
  float4 b = *(const float4*)(src + 4);
  f16x8 o;
  o[0] = (_Float16)a.x; o[1] = (_Float16)a.y; o[2] = (_Float16)a.z; o[3] = (_Float16)a.w;
  o[4] = (_Float16)b.x; o[5] = (_Float16)b.y; o[6] = (_Float16)b.z; o[7] = (_Float16)b.w;
  *(f16x8*)(xh + (size_t)nd * 128 + part * 8) = o;
}

// ---------------- pre-convert weights to f16 in LDS-staging order -----------
__global__ __launch_bounds__(256) void convert_w(const float* __restrict__ Wl,
    const float* __restrict__ Wr, _Float16* __restrict__ wh) {
  int qq = blockIdx.x * 256 + threadIdx.x;   // 0..4095
  int ks = qq >> 9, nf = (qq >> 6) & 7, l = qq & 63;
  int ncol = nf * 16 + (l & 15);
  int k0 = (ks & 3) * 32 + ((l >> 4) << 3);
  const float* wsrc = ((ks < 4) ? Wl : Wr) + ncol * 128 + k0;
  float4 a = *(const float4*)wsrc;
  float4 b = *(const float4*)(wsrc + 4);
  f16x8 w;
  w[0] = (_Float16)a.x; w[1] = (_Float16)a.y; w[2] = (_Float16)a.z; w[3] = (_Float16)a.w;
  w[4] = (_Float16)b.x; w[5] = (_Float16)b.y; w[6] = (_Float16)b.z; w[7] = (_Float16)b.w;
  *(f16x8*)(wh + (size_t)qq * 8) = w;
}

// ---------------- CSR build (layer 0 only), 3 phases ------------------------
__global__ __launch_bounds__(1024) void csr_hist(const int* __restrict__ src,
    const int* __restrict__ dst, int np, int* __restrict__ part) {
  __shared__ int hist[2048];
  int x = blockIdx.x;
  int s = x & 7, q = x >> 3;
  int b = q & (NSB - 1), gh = q >> 3;
  int g = gh * 8 + s;
  int tid = threadIdx.x;
  for (int i = tid; i < 2048; i += 1024) hist[i] = 0;
  __syncthreads();
  int e0 = g * ECAP + b * (ECAP / NSB);
  int nodebase = g * np;
  for (int e = tid; e < ECAP / NSB; e += 1024) {
    atomicAdd(&hist[dst[e0 + e] - nodebase], 1);
  }
  __syncthreads();
  for (int i = tid; i < np; i += 1024) part[((size_t)(g * NSB + b)) * 2048 + i] = hist[i];
}

__global__ __launch_bounds__(1024) void csr_scan(const int* __restrict__ part, int np,
    int* __restrict__ offb, int* __restrict__ deg, int* __restrict__ curs) {
  __shared__ int psum[1024];
  int g = blockIdx.x, tid = threadIdx.x;
  int i0 = 2 * tid, i1 = 2 * tid + 1;
  int p0[NSB], p1[NSB];
  int c0 = 0, c1 = 0;
#pragma unroll
  for (int b = 0; b < NSB; ++b) {
    p0[b] = (i0 < np) ? part[((size_t)(g * NSB + b)) * 2048 + i0] : 0;
    p1[b] = (i1 < np) ? part[((size_t)(g * NSB + b)) * 2048 + i1] : 0;
    c0 += p0[b]; c1 += p1[b];
  }
  int pair = c0 + c1;
  psum[tid] = pair;
  for (int s = 1; s < 1024; s <<= 1) {
    __syncthreads();
    int t = (tid >= s) ? psum[tid - s] : 0;
    __syncthreads();
    psum[tid] += t;
  }
  int excl = psum[tid] - pair;
  int ebase = g * ECAP;
  int nodebase = g * np;
  if (i0 < np) {
    int off = ebase + excl;
    offb[nodebase + i0] = off;
    deg[nodebase + i0] = c0;
    int cur = off;
#pragma unroll
    for (int b = 0; b < NSB; ++b) { curs[((size_t)(g * NSB + b)) * 2048 + i0] = cur; cur += p0[b]; }
  }
  if (i1 < np) {
    int off = ebase + excl + c0;
    offb[nodebase + i1] = off;
    deg[nodebase + i1] = c1;
    int cur = off;
#pragma unroll
    for (int b = 0; b < NSB; ++b) { curs[((size_t)(g * NSB + b)) * 2048 + i1] = cur; cur += p1[b]; }
  }
}

__global__ __launch_bounds__(1024) void csr_place(const int* __restrict__ src,
    const int* __restrict__ dst, int np, const int* __restrict__ curs,
    int* __restrict__ esort) {
  __shared__ int cur[2048];
  int x = blockIdx.x;
  int s = x & 7, q = x >> 3;
  int b = q & (NSB - 1), gh = q >> 3;
  int g = gh * 8 + s;
  int tid = threadIdx.x;
  for (int i = tid; i < np; i += 1024) cur[i] = curs[((size_t)(g * NSB + b)) * 2048 + i];
  __syncthreads();
  int e0 = g * ECAP + b * (ECAP / NSB);
  int nodebase = g * np;
  for (int e = tid; e < ECAP / NSB; e += 1024) {
    int ge = e0 + e;
    int p = atomicAdd(&cur[dst[ge] - nodebase], 1);
    esort[p] = src[ge];
  }
}

// ---------------- compose pool maps: A[v] = A[v]>=0 ? B[A[v]] : -1 ----------
__global__ __launch_bounds__(256) void compose_kernel(int* __restrict__ A,
    const int* __restrict__ B, int n) {
  int v = blockIdx.x * 256 + threadIdx.x;
  if (v >= n) return;
  int a = A[v];
  A[v] = (a >= 0) ? B[a] : -1;
}

// ---------------- aggregate (layer 0): mean over incoming edges --------------
__global__ __launch_bounds__(256) void aggregate_kernel(const _Float16* __restrict__ xh,
    const int* __restrict__ offb, const int* __restrict__ deg, const int* __restrict__ esrc,
    _Float16* __restrict__ meanh, int np, int C) {
  int bid = blockIdx.x;
  int s = bid & 7, q = bid >> 3;
  int gsub = q / C, chunk = q - gsub * C;
  int g = gsub * 8 + s;
  int wave = threadIdx.x >> 6, lane = threadIdx.x & 63;
  int sub = lane >> 4, l = lane & 15;
  int local = chunk * 16 + wave * 4 + sub;
  if (local >= np) return;
  int w = g * np + local;
  int b = offb[w], c = deg[w];
  int e = b + c;
  float acc[8] = {0.f, 0.f, 0.f, 0.f, 0.f, 0.f, 0.f, 0.f};
  int i = b;
  for (; i + 4 <= e; i += 4) {
    int s0 = esrc[i], s1 = esrc[i + 1], s2 = esrc[i + 2], s3 = esrc[i + 3];
    f16x8 v0 = *(const f16x8*)(xh + (size_t)s0 * 128 + l * 8);
    f16x8 v1 = *(const f16x8*)(xh + (size_t)s1 * 128 + l * 8);
    f16x8 v2 = *(const f16x8*)(xh + (size_t)s2 * 128 + l * 8);
    f16x8 v3 = *(const f16x8*)(xh + (size_t)s3 * 128 + l * 8);
    f16x8 t = (v0 + v1) + (v2 + v3);
#pragma unroll
    for (int j = 0; j < 8; ++j) acc[j] += (float)t[j];
  }
  for (; i < e; ++i) {
    int srcn = esrc[i];
    f16x8 v = *(const f16x8*)(xh + (size_t)srcn * 128 + l * 8);
#pragma unroll
    for (int j = 0; j < 8; ++j) acc[j] += (float)v[j];
  }
  float inv = 1.f / (float)(c > 0 ? c : 1);
  f16x8 o;
#pragma unroll
  for (int j = 0; j < 8; ++j) o[j] = (_Float16)(acc[j] * inv);
  *(f16x8*)(meanh + (size_t)w * 128 + l * 8) = o;
}

// ---------------- aggregate (layers 1/2): layer-0 CSR + composed NOO filter --
// node w (current id): orig o = orig[w]; iterate layer-0 segment of o;
// keep edges whose orig src survives (noo[so] >= 0), gather at current id.
__global__ __launch_bounds__(256) void aggregate_f(const _Float16* __restrict__ xh,
    const int* __restrict__ offb0, const int* __restrict__ deg0, const int* __restrict__ esort0,
    const int* __restrict__ orig, const int* __restrict__ noo,
    _Float16* __restrict__ meanh, int np, int C) {
  int bid = blockIdx.x;
  int s = bid & 7, q = bid >> 3;
  int gsub = q / C, chunk = q - gsub * C;
  int g = gsub * 8 + s;
  int wave = threadIdx.x >> 6, lane = threadIdx.x & 63;
  int sub = lane >> 4, l = lane & 15;
  int local = chunk * 16 + wave * 4 + sub;
  if (local >= np) return;
  int w = g * np + local;
  int o = orig[w];
  int b = offb0[o], c0 = deg0[o];
  int e = b + c0;
  float acc[8] = {0.f, 0.f, 0.f, 0.f, 0.f, 0.f, 0.f, 0.f};
  int cnt = 0;
  for (int i = b; i < e; ++i) {
    int sn = noo[esort0[i]];
    if (sn < 0) continue;
    ++cnt;
    f16x8 v = *(const f16x8*)(xh + (size_t)sn * 128 + l * 8);
#pragma unroll
    for (int j = 0; j < 8; ++j) acc[j] += (float)v[j];
  }
  float inv = 1.f / (float)(cnt > 0 ? cnt : 1);
  f16x8 ov;
#pragma unroll
  for (int j = 0; j < 8; ++j) ov[j] = (_Float16)(acc[j] * inv);
  *(f16x8*)(meanh + (size_t)w * 128 + l * 8) = ov;
}

// ---------------- fused SAGE transform + score ----------------
__global__ __launch_bounds__(256, 2) void sage_gemm(const _Float16* __restrict__ XH,
    const _Float16* MEANIN, _Float16* OUT, const _Float16* __restrict__ WH,
    const float* __restrict__ bl, const float* __restrict__ pw, float* __restrict__ sc,
    int n) {
  __shared__ _Float16 WB[4096 * 8];  // 64KB, layout [ks][nf][lane][8]
  int tid = threadIdx.x;
  for (int qq = tid; qq < 4096; qq += 256)
    *(f16x8*)(WB + qq * 8) = *(const f16x8*)(WH + (size_t)qq * 8);
  __syncthreads();
  int wave = tid >> 6, lane = tid & 63;
  int wrow0 = blockIdx.x * RPB + wave * 64;
  if (wrow0 >= n) return;
  int kb = (lane >> 4) << 3;
  int lr = lane & 15;
  f32x4 acc[4][8];
#pragma unroll
  for (int t = 0; t < 4; ++t)
#pragma unroll
    for (int nf = 0; nf < 8; ++nf) acc[t][nf] = (f32x4){0.f, 0.f, 0.f, 0.f};
#pragma unroll
  for (int ks = 0; ks < 8; ++ks) {
    const _Float16* A = (ks < 4) ? MEANIN : XH;
    const _Float16* ap = A + (size_t)(wrow0 + lr) * 128 + (ks & 3) * 32 + kb;
    f16x8 a0 = *(const f16x8*)(ap);
    f16x8 a1 = *(const f16x8*)(ap + 16 * 128);
    f16x8 a2 = *(const f16x8*)(ap + 32 * 128);
    f16x8 a3 = *(const f16x8*)(ap + 48 * 128);
#pragma unroll
    for (int nf = 0; nf < 8; ++nf) {
      f16x8 b = *(const f16x8*)(WB + ((ks * 8 + nf) * 64 + lane) * 8);
      acc[0][nf] = __builtin_amdgcn_mfma_f32_16x16x32_f16(a0, b, acc[0][nf], 0, 0, 0);
      acc[1][nf] = __builtin_amdgcn_mfma_f32_16x16x32_f16(a1, b, acc[1][nf], 0, 0, 0);
      acc[2][nf] = __builtin_amdgcn_mfma_f32_16x16x32_f16(a2, b, acc[2][nf], 0, 0, 0);
      acc[3][nf] = __builtin_amdgcn_mfma_f32_16x16x32_f16(a3, b, acc[3][nf], 0, 0, 0);
    }
  }
  float pwv[8], qn = 0.f;
#pragma unroll
  for (int nf = 0; nf < 8; ++nf) {
    pwv[nf] = pw[nf * 16 + lr];
    qn += pwv[nf] * pwv[nf];
  }
#pragma unroll
  for (int o = 1; o < 16; o <<= 1) qn += __shfl_xor(qn, o);
  float inv_n = 1.f / sqrtf(qn);
#pragma unroll
  for (int t = 0; t < 4; ++t) {
    int rbase = wrow0 + t * 16 + ((lane >> 4) << 2);
    float dot[4] = {0.f, 0.f, 0.f, 0.f};
#pragma unroll
    for (int nf = 0; nf < 8; ++nf) {
      int col = nf * 16 + lr;
      float bias = bl[col];
#pragma unroll
      for (int r = 0; r < 4; ++r) {
        float v = fmaxf(acc[t][nf][r] + bias, 0.f);
        OUT[(size_t)(rbase + r) * 128 + col] = (_Float16)v;
        dot[r] += v * pwv[nf];
      }
    }
#pragma unroll
    for (int r = 0; r < 4; ++r) {
#pragma unroll
      for (int o = 1; o < 16; o <<= 1) dot[r] += __shfl_xor(dot[r], o);
    }
    if (lr == 0) {
#pragma unroll
      for (int r = 0; r < 4; ++r) sc[rbase + r] = tanhf(dot[r] * inv_n);
    }
  }
}

// ---------------- per-graph top-k: hybrid LDS/register bitonic ----------------
__global__ __launch_bounds__(1024) void topk_kernel(const float* __restrict__ sc, int n_per, int k,
    float* __restrict__ ts, int* __restrict__ perm, int* __restrict__ noo) {
  __shared__ unsigned long long L[2048];
  int g = blockIdx.x;
  int tid = threadIdx.x;
  int lane = tid & 63, wave = tid >> 6;
  int i0 = wave * 128 + lane;
  int i1 = i0 + 64;
  const float* scg = sc + g * n_per;
  auto keyize = [&](int i) -> unsigned long long {
    float f = (i < n_per) ? scg[i] : -FLT_MAX;
    unsigned u = __float_as_uint(f);
    u = (u & 0x80000000u) ? ~u : (u | 0x80000000u);  // monotone float->uint map
    return ((unsigned long long)u << 32) | (unsigned)(2047 - i);
  };
  unsigned long long a = keyize(i0), b = keyize(i1);
#pragma clang loop unroll(disable)
  for (unsigned kk = 2; kk <= 2048; kk <<= 1) {
#pragma clang loop unroll(disable)
    for (unsigned j = kk >> 1; j >= 128; j >>= 1) {
      L[i0] = a; L[i1] = b;
      __syncthreads();
      unsigned long long pa = L[i0 ^ j], pb = L[i1 ^ j];
      bool dA = ((i0 & kk) == 0), lA = ((i0 & j) == 0);
      if ((dA == lA) ? (pa > a) : (pa < a)) a = pa;
      bool dB = ((i1 & kk) == 0), lB = ((i1 & j) == 0);
      if ((dB == lB) ? (pb > b) : (pb < b)) b = pb;
      __syncthreads();
    }
    if (kk >= 128) {
      bool desc = ((i0 & kk) == 0);
      if ((a < b) == desc) { unsigned long long t = a; a = b; b = t; }
    }
    unsigned jtop = (kk >> 1 < 32u) ? (kk >> 1) : 32u;
#pragma clang loop unroll(disable)
    for (unsigned j = jtop; j >= 1; j >>= 1) {
      unsigned long long oa = __shfl_xor(a, (int)j);
      unsigned long long ob = __shfl_xor(b, (int)j);
      bool low = ((lane & j) == 0);
      bool dA = ((i0 & kk) == 0);
      if ((dA == low) ? (oa > a) : (oa < a)) a = oa;
      bool dB = ((i1 & kk) == 0);
      if ((dB == low) ? (ob > b) : (ob < b)) b = ob;
    }
  }
  auto emit = [&](unsigned long long v, int rank) {
    int orig = 2047 - (int)(v & 0xFFFFFFFFu);
    if (orig < n_per) {
      if (rank < k) {
        int ng = g * k + rank;
        ts[ng] = scg[orig];
        perm[ng] = g * n_per + orig;
        noo[g * n_per + orig] = ng;
      } else {
        noo[g * n_per + orig] = -1;
      }
    }
  };
  emit(a, i0);
  emit(b, i1);
}

// ---------------- gather + scale + ORIG compose ------------------------------
// xh[v] = out[perm[v]] * ts[v];  orig_out[v] = orig_in ? orig_in[perm[v]] : perm[v]
__global__ __launch_bounds__(256) void gather_kernel(const _Float16* __restrict__ xold,
    const int* __restrict__ perm, const float* __restrict__ ts, _Float16* __restrict__ xh,
    const int* __restrict__ orig_in, int* __restrict__ orig_out, int n_new) {
  int idx = blockIdx.x * 256 + threadIdx.x;
  int v = idx >> 4, part = idx & 15;
  if (v >= n_new) return;
  int p = perm[v];
  if (part == 0) orig_out[v] = orig_in ? orig_in[p] : p;
  float t = ts[v];
  f16x8 a = *(const f16x8*)(xold + (size_t)p * 128 + part * 8);
  f16x8 o;
#pragma unroll
  for (int j = 0; j < 8; ++j) o[j] = (_Float16)((float)a[j] * t);
  *(f16x8*)(xh + (size_t)v * 128 + part * 8) = o;
}

// ---------------- readout stage 1: per-(graph,slice) partial max/sum ----------------
__global__ __launch_bounds__(256) void readout_part(const _Float16* __restrict__ x, int k,
    float* __restrict__ pmax, float* __restrict__ psum) {
  int g = blockIdx.x >> 4;           // / RSLICES
  int slice = blockIdx.x & (RSLICES - 1);
  int d = threadIdx.x & 127;
  int half = threadIdx.x >> 7;       // 0 or 1
  int rpb = (k + RSLICES - 1) / RSLICES;
  int r0 = slice * rpb;
  int r1 = r0 + rpb; if (r1 > k) r1 = k;
  float vmax = -FLT_MAX, vs = 0.f;
  for (int r = r0 + half; r < r1; r += 2) {
    float v = (float)x[((size_t)g * k + r) * 128 + d];
    vmax = fmaxf(vmax, v);
    vs += v;
  }
  __shared__ float smax[256], ssum[256];
  smax[threadIdx.x] = vmax;
  ssum[threadIdx.x] = vs;
  __syncthreads();
  if (threadIdx.x < 128) {
    vmax = fmaxf(smax[threadIdx.x], smax[threadIdx.x + 128]);
    vs = ssum[threadIdx.x] + ssum[threadIdx.x + 128];
    pmax[(size_t)(g * RSLICES + slice) * 128 + d] = vmax;
    psum[(size_t)(g * RSLICES + slice) * 128 + d] = vs;
  }
}

// ---------------- readout stage 2: combine slices, h[g] += [max, mean] ----------------
__global__ __launch_bounds__(256) void readout_comb(const float* __restrict__ pmax,
    const float* __restrict__ psum, int k, float* __restrict__ h) {
  int idx = blockIdx.x * 256 + threadIdx.x;  // 64*128
  int g = idx >> 7, d = idx & 127;
  float vmax = -FLT_MAX, vs = 0.f;
#pragma unroll
  for (int s = 0; s < RSLICES; ++s) {
    vmax = fmaxf(vmax, pmax[(size_t)(g * RSLICES + s) * 128 + d]);
    vs += psum[(size_t)(g * RSLICES + s) * 128 + d];
  }
  h[g * 256 + d] += vmax;
  h[g * 256 + 128 + d] += vs / (float)k;
}

// ---------------- final MLP ----------------
__global__ __launch_bounds__(256) void mlp1(const float* __restrict__ h, const float* __restrict__ W1,
    const float* __restrict__ b1, float* __restrict__ h1) {
  int o = blockIdx.x * 256 + threadIdx.x;  // 64*128
  int g = o >> 7, j = o & 127;
  const float* hp = h + g * 256;
  const float* wp = W1 + j * 256;
  float a = b1[j];
  for (int c = 0; c < 256; ++c) a += hp[c] * wp[c];
  h1[o] = fmaxf(a, 0.f);
}

__global__ __launch_bounds__(256) void mlp2(const float* __restrict__ h1, const float* __restrict__ W2,
    const float* __restrict__ b2, float* __restrict__ h2) {
  int o = blockIdx.x * 256 + threadIdx.x;  // 64*64
  int g = o >> 6, j = o & 63;
  const float* hp = h1 + g * 128;
  const float* wp = W2 + j * 128;
  float a = b2[j];
  for (int c = 0; c < 128; ++c) a += hp[c] * wp[c];
  h2[o] = fmaxf(a, 0.f);
}

__global__ __launch_bounds__(64) void mlp3(const float* __restrict__ h2, const float* __restrict__ W3,
    const float* __restrict__ b3, float* __restrict__ out) {
  int g = threadIdx.x;
  if (g >= 64) return;
  const float* hp = h2 + g * 64;
  float a = b3[0];
  for (int c = 0; c < 64; ++c) a += hp[c] * W3[c];
  out[g] = 1.f / (1.f + expf(-a));
}

extern "C" void kernel_launch(void* const* d_in, const int* in_sizes, int n_in,
                              void* d_out, int out_size, void* d_ws, size_t ws_size,
                              hipStream_t stream) {
  const int* node_ids = (const int*)d_in[0];
  const int* ei = (const int*)d_in[1];
  const float* emb = (const float*)d_in[3];
  const float* W[3][4] = {
      {(const float*)d_in[4], (const float*)d_in[5], (const float*)d_in[6], (const float*)d_in[7]},
      {(const float*)d_in[8], (const float*)d_in[9], (const float*)d_in[10], (const float*)d_in[11]},
      {(const float*)d_in[12], (const float*)d_in[13], (const float*)d_in[14], (const float*)d_in[15]}};
  const float* W1 = (const float*)d_in[16];
  const float* b1 = (const float*)d_in[17];
  const float* W2 = (const float*)d_in[18];
  const float* b2 = (const float*)d_in[19];
  const float* W3 = (const float*)d_in[20];
  const float* b3 = (const float*)d_in[21];
  float* out = (float*)d_out;

  const int E = NEDGES;
  char* ws = (char*)d_ws;
  size_t o = 0;
  auto alloc = [&](size_t bytes) { void* p = ws + o; o = (o + bytes + 255) & ~(size_t)255; return p; };
  _Float16* XH = (_Float16*)alloc((size_t)NNODES * 128 * 2);
  _Float16* MEANH = (_Float16*)alloc((size_t)NNODES * 128 * 2);
  int* ESORT = (int*)alloc((size_t)E * 4);
  int* PART = (int*)alloc((size_t)GRAPHS * NSB * 2048 * 4);
  int* CURS = (int*)alloc((size_t)GRAPHS * NSB * 2048 * 4);
  int* OFFB = (int*)alloc((size_t)NNODES * 4);
  int* DEG = (int*)alloc((size_t)NNODES * 4);
  float* SC = (float*)alloc((size_t)NNODES * 4);
  float* TS = (float*)alloc((size_t)NNODES * 4);
  int* PERM = (int*)alloc((size_t)NNODES * 4);
  int* NOOA = (int*)alloc((size_t)NNODES * 4);
  int* NOOB = (int*)alloc((size_t)NNODES * 4);
  int* ORIGA = (int*)alloc((size_t)NNODES * 4);
  int* ORIGB = (int*)alloc((size_t)NNODES * 4);
  _Float16* WH0 = (_Float16*)alloc(4096 * 8 * 2);
  _Float16* WH1 = (_Float16*)alloc(4096 * 8 * 2);
  _Float16* WH2 = (_Float16*)alloc(4096 * 8 * 2);
  float* PMAX = (float*)alloc((size_t)GRAPHS * RSLICES * 128 * 4);
  float* PSUM = (float*)alloc((size_t)GRAPHS * RSLICES * 128 * 4);
  float* H = (float*)alloc(64 * 256 * 4);
  float* H1 = (float*)alloc(64 * 128 * 4);
  float* H2 = (float*)alloc(64 * 64 * 4);

  embed_kernel<<<NNODES * 16 / 256, 256, 0, stream>>>(node_ids, emb, XH);
  hipMemsetAsync(H, 0, 64 * 256 * 4, stream);
  convert_w<<<16, 256, 0, stream>>>(W[0][0], W[0][1], WH0);
  convert_w<<<16, 256, 0, stream>>>(W[1][0], W[1][1], WH1);
  convert_w<<<16, 256, 0, stream>>>(W[2][0], W[2][1], WH2);

  // layer-0 CSR (built once; reused with NOO filter by layers 1/2)
  const int* src = ei;
  const int* dst = ei + E;
  csr_hist<<<GRAPHS * NSB, 1024, 0, stream>>>(src, dst, NPG, PART);
  csr_scan<<<GRAPHS, 1024, 0, stream>>>(PART, NPG, OFFB, DEG, CURS);
  csr_place<<<GRAPHS * NSB, 1024, 0, stream>>>(src, dst, NPG, CURS, ESORT);

  struct LayerP { int n, k; };                 // n = current node count; k = keep per graph
  LayerP L[3] = {{131072, 1639}, {104896, 1312}, {83968, 1050}};
  _Float16* WHs[3] = {WH0, WH1, WH2};
  int* ORIG_cur = ORIGA;   // maps current ids -> original ids (valid for li>=1)
  int* ORIG_next = ORIGB;

  for (int li = 0; li < 3; ++li) {
    int n = L[li].n, k = L[li].k;
    int np = n / 64;
    int n_new = 64 * k;
    const float *bl = W[li][2], *pw = W[li][3];

    int C = (np + 15) / 16;
    if (li == 0) {
      aggregate_kernel<<<64 * C, 256, 0, stream>>>(XH, OFFB, DEG, ESORT, MEANH, np, C);
    } else {
      aggregate_f<<<64 * C, 256, 0, stream>>>(XH, OFFB, DEG, ESORT, ORIG_cur, NOOA,
                                              MEANH, np, C);
    }
    sage_gemm<<<(n + RPB - 1) / RPB, 256, 0, stream>>>(XH, MEANH, MEANH, WHs[li], bl, pw, SC, n);
    topk_kernel<<<GRAPHS, 1024, 0, stream>>>(SC, np, k, TS, PERM, (li == 0) ? NOOA : NOOB);
    gather_kernel<<<n_new * 16 / 256, 256, 0, stream>>>(MEANH, PERM, TS, XH,
        (li == 0) ? nullptr : ORIG_cur, ORIG_next, n_new);
    { int* t = ORIG_cur; ORIG_cur = ORIG_next; ORIG_next = t; }
    readout_part<<<GRAPHS * RSLICES, 256, 0, stream>>>(XH, k, PMAX, PSUM);
    readout_comb<<<32, 256, 0, stream>>>(PMAX, PSUM, k, H);
    if (li == 1) compose_kernel<<<NNODES / 256, 256, 0, stream>>>(NOOA, NOOB, NNODES);
  }

  mlp1<<<32, 256, 0, stream>>>(H, W1, b1, H1);
  mlp2<<<16, 256, 0, stream>>>(H1, W2, b2, H2);
  mlp3<<<1, 64, 0, stream>>>(H2, W3, b3, out);
}

// Round 12
// 397.634 us; speedup vs baseline: 1.0825x; 1.0825x over previous
//
#include <hip/hip_runtime.h>
#include <hip/hip_bf16.h>
#include <float.h>

typedef _Float16 f16x8 __attribute__((ext_vector_type(8)));
typedef float f32x4 __attribute__((ext_vector_type(4)));

#define GRAPHS 64
#define NPG 2048
#define DIM 128
#define NNODES (GRAPHS * NPG)
#define NEDGES (NNODES * 16)
#define ECAP 32768   // edges per graph
#define NSB 8        // sub-blocks per graph for CSR build
#define RSLICES 16
#define RPB 256      // rows per block in sage_gemm

// ---------------- embed: xh[i] = (f16) emb[node_ids[i]] ----------------
__global__ __launch_bounds__(256) void embed_kernel(const int* __restrict__ ids,
    const float* __restrict__ emb, _Float16* __restrict__ xh) {
  int idx = blockIdx.x * 256 + threadIdx.x;
  int nd = idx >> 4, part = idx & 15;
  int id = ids[nd];
  const float* src = emb + (size_t)id * 128 + part * 8;
  float4 a = *(const float4*)(src);
  float4 b = *(const float4*)(src + 4);
  f16x8 o;
  o[0] = (_Float16)a.x; o[1] = (_Float16)a.y; o[2] = (_Float16)a.z; o[3] = (_Float16)a.w;
  o[4] = (_Float16)b.x; o[5] = (_Float16)b.y; o[6] = (_Float16)b.z; o[7] = (_Float16)b.w;
  *(f16x8*)(xh + (size_t)nd * 128 + part * 8) = o;
}

// ---------------- pre-convert weights to f16 in LDS-staging order -----------
__global__ __launch_bounds__(256) void convert_w(const float* __restrict__ Wl,
    const float* __restrict__ Wr, _Float16* __restrict__ wh) {
  int qq = blockIdx.x * 256 + threadIdx.x;   // 0..4095
  int ks = qq >> 9, nf = (qq >> 6) & 7, l = qq & 63;
  int ncol = nf * 16 + (l & 15);
  int k0 = (ks & 3) * 32 + ((l >> 4) << 3);
  const float* wsrc = ((ks < 4) ? Wl : Wr) + ncol * 128 + k0;
  float4 a = *(const float4*)wsrc;
  float4 b = *(const float4*)(wsrc + 4);
  f16x8 w;
  w[0] = (_Float16)a.x; w[1] = (_Float16)a.y; w[2] = (_Float16)a.z; w[3] = (_Float16)a.w;
  w[4] = (_Float16)b.x; w[5] = (_Float16)b.y; w[6] = (_Float16)b.z; w[7] = (_Float16)b.w;
  *(f16x8*)(wh + (size_t)qq * 8) = w;
}

// ---------------- CSR build (layer 0 only), 3 phases ------------------------
__global__ __launch_bounds__(1024) void csr_hist(const int* __restrict__ src,
    const int* __restrict__ dst, int np, int* __restrict__ part) {
  __shared__ int hist[2048];
  int x = blockIdx.x;
  int s = x & 7, q = x >> 3;
  int b = q & (NSB - 1), gh = q >> 3;
  int g = gh * 8 + s;
  int tid = threadIdx.x;
  for (int i = tid; i < 2048; i += 1024) hist[i] = 0;
  __syncthreads();
  int e0 = g * ECAP + b * (ECAP / NSB);
  int nodebase = g * np;
  for (int e = tid; e < ECAP / NSB; e += 1024) {
    atomicAdd(&hist[dst[e0 + e] - nodebase], 1);
  }
  __syncthreads();
  for (int i = tid; i < np; i += 1024) part[((size_t)(g * NSB + b)) * 2048 + i] = hist[i];
}

__global__ __launch_bounds__(1024) void csr_scan(const int* __restrict__ part, int np,
    int* __restrict__ offb, int* __restrict__ deg, int* __restrict__ curs) {
  __shared__ int psum[1024];
  int g = blockIdx.x, tid = threadIdx.x;
  int i0 = 2 * tid, i1 = 2 * tid + 1;
  int p0[NSB], p1[NSB];
  int c0 = 0, c1 = 0;
#pragma unroll
  for (int b = 0; b < NSB; ++b) {
    p0[b] = (i0 < np) ? part[((size_t)(g * NSB + b)) * 2048 + i0] : 0;
    p1[b] = (i1 < np) ? part[((size_t)(g * NSB + b)) * 2048 + i1] : 0;
    c0 += p0[b]; c1 += p1[b];
  }
  int pair = c0 + c1;
  psum[tid] = pair;
  for (int s = 1; s < 1024; s <<= 1) {
    __syncthreads();
    int t = (tid >= s) ? psum[tid - s] : 0;
    __syncthreads();
    psum[tid] += t;
  }
  int excl = psum[tid] - pair;
  int ebase = g * ECAP;
  int nodebase = g * np;
  if (i0 < np) {
    int off = ebase + excl;
    offb[nodebase + i0] = off;
    deg[nodebase + i0] = c0;
    int cur = off;
#pragma unroll
    for (int b = 0; b < NSB; ++b) { curs[((size_t)(g * NSB + b)) * 2048 + i0] = cur; cur += p0[b]; }
  }
  if (i1 < np) {
    int off = ebase + excl + c0;
    offb[nodebase + i1] = off;
    deg[nodebase + i1] = c1;
    int cur = off;
#pragma unroll
    for (int b = 0; b < NSB; ++b) { curs[((size_t)(g * NSB + b)) * 2048 + i1] = cur; cur += p1[b]; }
  }
}

__global__ __launch_bounds__(1024) void csr_place(const int* __restrict__ src,
    const int* __restrict__ dst, int np, const int* __restrict__ curs,
    int* __restrict__ esort) {
  __shared__ int cur[2048];
  int x = blockIdx.x;
  int s = x & 7, q = x >> 3;
  int b = q & (NSB - 1), gh = q >> 3;
  int g = gh * 8 + s;
  int tid = threadIdx.x;
  for (int i = tid; i < np; i += 1024) cur[i] = curs[((size_t)(g * NSB + b)) * 2048 + i];
  __syncthreads();
  int e0 = g * ECAP + b * (ECAP / NSB);
  int nodebase = g * np;
  for (int e = tid; e < ECAP / NSB; e += 1024) {
    int ge = e0 + e;
    int p = atomicAdd(&cur[dst[ge] - nodebase], 1);
    esort[p] = src[ge];
  }
}

// ---------------- compose pool maps: A[v] = A[v]>=0 ? B[A[v]] : -1 ----------
__global__ __launch_bounds__(256) void compose_kernel(int* __restrict__ A,
    const int* __restrict__ B, int n) {
  int v = blockIdx.x * 256 + threadIdx.x;
  if (v >= n) return;
  int a = A[v];
  A[v] = (a >= 0) ? B[a] : -1;
}

// ---------------- aggregate (layer 0): mean over incoming edges --------------
__global__ __launch_bounds__(256) void aggregate_kernel(const _Float16* __restrict__ xh,
    const int* __restrict__ offb, const int* __restrict__ deg, const int* __restrict__ esrc,
    _Float16* __restrict__ meanh, int np, int C) {
  int bid = blockIdx.x;
  int s = bid & 7, q = bid >> 3;
  int gsub = q / C, chunk = q - gsub * C;
  int g = gsub * 8 + s;
  int wave = threadIdx.x >> 6, lane = threadIdx.x & 63;
  int sub = lane >> 4, l = lane & 15;
  int local = chunk * 16 + wave * 4 + sub;
  if (local >= np) return;
  int w = g * np + local;
  int b = offb[w], c = deg[w];
  int e = b + c;
  float acc[8] = {0.f, 0.f, 0.f, 0.f, 0.f, 0.f, 0.f, 0.f};
  int i = b;
  for (; i + 4 <= e; i += 4) {
    int s0 = esrc[i], s1 = esrc[i + 1], s2 = esrc[i + 2], s3 = esrc[i + 3];
    f16x8 v0 = *(const f16x8*)(xh + (size_t)s0 * 128 + l * 8);
    f16x8 v1 = *(const f16x8*)(xh + (size_t)s1 * 128 + l * 8);
    f16x8 v2 = *(const f16x8*)(xh + (size_t)s2 * 128 + l * 8);
    f16x8 v3 = *(const f16x8*)(xh + (size_t)s3 * 128 + l * 8);
    f16x8 t = (v0 + v1) + (v2 + v3);
#pragma unroll
    for (int j = 0; j < 8; ++j) acc[j] += (float)t[j];
  }
  for (; i < e; ++i) {
    int srcn = esrc[i];
    f16x8 v = *(const f16x8*)(xh + (size_t)srcn * 128 + l * 8);
#pragma unroll
    for (int j = 0; j < 8; ++j) acc[j] += (float)v[j];
  }
  float inv = 1.f / (float)(c > 0 ? c : 1);
  f16x8 o;
#pragma unroll
  for (int j = 0; j < 8; ++j) o[j] = (_Float16)(acc[j] * inv);
  *(f16x8*)(meanh + (size_t)w * 128 + l * 8) = o;
}

// ---------------- aggregate (layers 1/2): layer-0 CSR + composed NOO filter --
// 4-edge ILP batch: 4 noo gathers in flight, then up to 4 predicated xh gathers.
__global__ __launch_bounds__(256) void aggregate_f(const _Float16* __restrict__ xh,
    const int* __restrict__ offb0, const int* __restrict__ deg0, const int* __restrict__ esort0,
    const int* __restrict__ orig, const int* __restrict__ noo,
    _Float16* __restrict__ meanh, int np, int C) {
  int bid = blockIdx.x;
  int s = bid & 7, q = bid >> 3;
  int gsub = q / C, chunk = q - gsub * C;
  int g = gsub * 8 + s;
  int wave = threadIdx.x >> 6, lane = threadIdx.x & 63;
  int sub = lane >> 4, l = lane & 15;
  int local = chunk * 16 + wave * 4 + sub;
  if (local >= np) return;
  int w = g * np + local;
  int o = orig[w];
  int b = offb0[o], c0 = deg0[o];
  int e = b + c0;
  float acc[8] = {0.f, 0.f, 0.f, 0.f, 0.f, 0.f, 0.f, 0.f};
  int cnt = 0;
  const f16x8 zero = {(_Float16)0.f, (_Float16)0.f, (_Float16)0.f, (_Float16)0.f,
                      (_Float16)0.f, (_Float16)0.f, (_Float16)0.f, (_Float16)0.f};
  int i = b;
  for (; i + 4 <= e; i += 4) {
    int s0 = esort0[i], s1 = esort0[i + 1], s2 = esort0[i + 2], s3 = esort0[i + 3];
    int n0 = noo[s0], n1 = noo[s1], n2 = noo[s2], n3 = noo[s3];
    f16x8 v0 = zero, v1 = zero, v2 = zero, v3 = zero;
    if (n0 >= 0) v0 = *(const f16x8*)(xh + (size_t)n0 * 128 + l * 8);
    if (n1 >= 0) v1 = *(const f16x8*)(xh + (size_t)n1 * 128 + l * 8);
    if (n2 >= 0) v2 = *(const f16x8*)(xh + (size_t)n2 * 128 + l * 8);
    if (n3 >= 0) v3 = *(const f16x8*)(xh + (size_t)n3 * 128 + l * 8);
    cnt += (n0 >= 0) + (n1 >= 0) + (n2 >= 0) + (n3 >= 0);
    f16x8 t = (v0 + v1) + (v2 + v3);
#pragma unroll
    for (int j = 0; j < 8; ++j) acc[j] += (float)t[j];
  }
  for (; i < e; ++i) {
    int sn = noo[esort0[i]];
    if (sn < 0) continue;
    ++cnt;
    f16x8 v = *(const f16x8*)(xh + (size_t)sn * 128 + l * 8);
#pragma unroll
    for (int j = 0; j < 8; ++j) acc[j] += (float)v[j];
  }
  float inv = 1.f / (float)(cnt > 0 ? cnt : 1);
  f16x8 ov;
#pragma unroll
  for (int j = 0; j < 8; ++j) ov[j] = (_Float16)(acc[j] * inv);
  *(f16x8*)(meanh + (size_t)w * 128 + l * 8) = ov;
}

// ---------------- fused SAGE transform + score ----------------
__global__ __launch_bounds__(256, 2) void sage_gemm(const _Float16* __restrict__ XH,
    const _Float16* MEANIN, _Float16* OUT, const _Float16* __restrict__ WH,
    const float* __restrict__ bl, const float* __restrict__ pw, float* __restrict__ sc,
    int n) {
  __shared__ _Float16 WB[4096 * 8];  // 64KB, layout [ks][nf][lane][8]
  int tid = threadIdx.x;
  for (int qq = tid; qq < 4096; qq += 256)
    *(f16x8*)(WB + qq * 8) = *(const f16x8*)(WH + (size_t)qq * 8);
  __syncthreads();
  int wave = tid >> 6, lane = tid & 63;
  int wrow0 = blockIdx.x * RPB + wave * 64;
  if (wrow0 >= n) return;
  int kb = (lane >> 4) << 3;
  int lr = lane & 15;
  f32x4 acc[4][8];
#pragma unroll
  for (int t = 0; t < 4; ++t)
#pragma unroll
    for (int nf = 0; nf < 8; ++nf) acc[t][nf] = (f32x4){0.f, 0.f, 0.f, 0.f};
#pragma unroll
  for (int ks = 0; ks < 8; ++ks) {
    const _Float16* A = (ks < 4) ? MEANIN : XH;
    const _Float16* ap = A + (size_t)(wrow0 + lr) * 128 + (ks & 3) * 32 + kb;
    f16x8 a0 = *(const f16x8*)(ap);
    f16x8 a1 = *(const f16x8*)(ap + 16 * 128);
    f16x8 a2 = *(const f16x8*)(ap + 32 * 128);
    f16x8 a3 = *(const f16x8*)(ap + 48 * 128);
#pragma unroll
    for (int nf = 0; nf < 8; ++nf) {
      f16x8 b = *(const f16x8*)(WB + ((ks * 8 + nf) * 64 + lane) * 8);
      acc[0][nf] = __builtin_amdgcn_mfma_f32_16x16x32_f16(a0, b, acc[0][nf], 0, 0, 0);
      acc[1][nf] = __builtin_amdgcn_mfma_f32_16x16x32_f16(a1, b, acc[1][nf], 0, 0, 0);
      acc[2][nf] = __builtin_amdgcn_mfma_f32_16x16x32_f16(a2, b, acc[2][nf], 0, 0, 0);
      acc[3][nf] = __builtin_amdgcn_mfma_f32_16x16x32_f16(a3, b, acc[3][nf], 0, 0, 0);
    }
  }
  float pwv[8], qn = 0.f;
#pragma unroll
  for (int nf = 0; nf < 8; ++nf) {
    pwv[nf] = pw[nf * 16 + lr];
    qn += pwv[nf] * pwv[nf];
  }
#pragma unroll
  for (int o = 1; o < 16; o <<= 1) qn += __shfl_xor(qn, o);
  float inv_n = 1.f / sqrtf(qn);
#pragma unroll
  for (int t = 0; t < 4; ++t) {
    int rbase = wrow0 + t * 16 + ((lane >> 4) << 2);
    float dot[4] = {0.f, 0.f, 0.f, 0.f};
#pragma unroll
    for (int nf = 0; nf < 8; ++nf) {
      int col = nf * 16 + lr;
      float bias = bl[col];
#pragma unroll
      for (int r = 0; r < 4; ++r) {
        float v = fmaxf(acc[t][nf][r] + bias, 0.f);
        OUT[(size_t)(rbase + r) * 128 + col] = (_Float16)v;
        dot[r] += v * pwv[nf];
      }
    }
#pragma unroll
    for (int r = 0; r < 4; ++r) {
#pragma unroll
      for (int o = 1; o < 16; o <<= 1) dot[r] += __shfl_xor(dot[r], o);
    }
    if (lr == 0) {
#pragma unroll
      for (int r = 0; r < 4; ++r) sc[rbase + r] = tanhf(dot[r] * inv_n);
    }
  }
}

// ---------------- per-graph top-k: hybrid LDS/register bitonic ----------------
__global__ __launch_bounds__(1024) void topk_kernel(const float* __restrict__ sc, int n_per, int k,
    float* __restrict__ ts, int* __restrict__ perm, int* __restrict__ noo) {
  __shared__ unsigned long long L[2048];
  int g = blockIdx.x;
  int tid = threadIdx.x;
  int lane = tid & 63, wave = tid >> 6;
  int i0 = wave * 128 + lane;
  int i1 = i0 + 64;
  const float* scg = sc + g * n_per;
  auto keyize = [&](int i) -> unsigned long long {
    float f = (i < n_per) ? scg[i] : -FLT_MAX;
    unsigned u = __float_as_uint(f);
    u = (u & 0x80000000u) ? ~u : (u | 0x80000000u);  // monotone float->uint map
    return ((unsigned long long)u << 32) | (unsigned)(2047 - i);
  };
  unsigned long long a = keyize(i0), b = keyize(i1);
#pragma clang loop unroll(disable)
  for (unsigned kk = 2; kk <= 2048; kk <<= 1) {
#pragma clang loop unroll(disable)
    for (unsigned j = kk >> 1; j >= 128; j >>= 1) {
      L[i0] = a; L[i1] = b;
      __syncthreads();
      unsigned long long pa = L[i0 ^ j], pb = L[i1 ^ j];
      bool dA = ((i0 & kk) == 0), lA = ((i0 & j) == 0);
      if ((dA == lA) ? (pa > a) : (pa < a)) a = pa;
      bool dB = ((i1 & kk) == 0), lB = ((i1 & j) == 0);
      if ((dB == lB) ? (pb > b) : (pb < b)) b = pb;
      __syncthreads();
    }
    if (kk >= 128) {
      bool desc = ((i0 & kk) == 0);
      if ((a < b) == desc) { unsigned long long t = a; a = b; b = t; }
    }
    unsigned jtop = (kk >> 1 < 32u) ? (kk >> 1) : 32u;
#pragma clang loop unroll(disable)
    for (unsigned j = jtop; j >= 1; j >>= 1) {
      unsigned long long oa = __shfl_xor(a, (int)j);
      unsigned long long ob = __shfl_xor(b, (int)j);
      bool low = ((lane & j) == 0);
      bool dA = ((i0 & kk) == 0);
      if ((dA == low) ? (oa > a) : (oa < a)) a = oa;
      bool dB = ((i1 & kk) == 0);
      if ((dB == low) ? (ob > b) : (ob < b)) b = ob;
    }
  }
  auto emit = [&](unsigned long long v, int rank) {
    int orig = 2047 - (int)(v & 0xFFFFFFFFu);
    if (orig < n_per) {
      if (rank < k) {
        int ng = g * k + rank;
        ts[ng] = scg[orig];
        perm[ng] = g * n_per + orig;
        noo[g * n_per + orig] = ng;
      } else {
        noo[g * n_per + orig] = -1;
      }
    }
  };
  emit(a, i0);
  emit(b, i1);
}

// ---------------- gather + scale + ORIG compose ------------------------------
__global__ __launch_bounds__(256) void gather_kernel(const _Float16* __restrict__ xold,
    const int* __restrict__ perm, const float* __restrict__ ts, _Float16* __restrict__ xh,
    const int* __restrict__ orig_in, int* __restrict__ orig_out, int n_new) {
  int idx = blockIdx.x * 256 + threadIdx.x;
  int v = idx >> 4, part = idx & 15;
  if (v >= n_new) return;
  int p = perm[v];
  if (part == 0) orig_out[v] = orig_in ? orig_in[p] : p;
  float t = ts[v];
  f16x8 a = *(const f16x8*)(xold + (size_t)p * 128 + part * 8);
  f16x8 o;
#pragma unroll
  for (int j = 0; j < 8; ++j) o[j] = (_Float16)((float)a[j] * t);
  *(f16x8*)(xh + (size_t)v * 128 + part * 8) = o;
}

// ---------------- readout stage 1: per-(graph,slice) partial max/sum ----------------
__global__ __launch_bounds__(256) void readout_part(const _Float16* __restrict__ x, int k,
    float* __restrict__ pmax, float* __restrict__ psum) {
  int g = blockIdx.x >> 4;           // / RSLICES
  int slice = blockIdx.x & (RSLICES - 1);
  int d = threadIdx.x & 127;
  int half = threadIdx.x >> 7;       // 0 or 1
  int rpb = (k + RSLICES - 1) / RSLICES;
  int r0 = slice * rpb;
  int r1 = r0 + rpb; if (r1 > k) r1 = k;
  float vmax = -FLT_MAX, vs = 0.f;
  for (int r = r0 + half; r < r1; r += 2) {
    float v = (float)x[((size_t)g * k + r) * 128 + d];
    vmax = fmaxf(vmax, v);
    vs += v;
  }
  __shared__ float smax[256], ssum[256];
  smax[threadIdx.x] = vmax;
  ssum[threadIdx.x] = vs;
  __syncthreads();
  if (threadIdx.x < 128) {
    vmax = fmaxf(smax[threadIdx.x], smax[threadIdx.x + 128]);
    vs = ssum[threadIdx.x] + ssum[threadIdx.x + 128];
    pmax[(size_t)(g * RSLICES + slice) * 128 + d] = vmax;
    psum[(size_t)(g * RSLICES + slice) * 128 + d] = vs;
  }
}

// ---------------- readout stage 2: combine slices, h[g] += [max, mean] ----------------
__global__ __launch_bounds__(256) void readout_comb(const float* __restrict__ pmax,
    const float* __restrict__ psum, int k, float* __restrict__ h) {
  int idx = blockIdx.x * 256 + threadIdx.x;  // 64*128
  int g = idx >> 7, d = idx & 127;
  float vmax = -FLT_MAX, vs = 0.f;
#pragma unroll
  for (int s = 0; s < RSLICES; ++s) {
    vmax = fmaxf(vmax, pmax[(size_t)(g * RSLICES + s) * 128 + d]);
    vs += psum[(size_t)(g * RSLICES + s) * 128 + d];
  }
  h[g * 256 + d] += vmax;
  h[g * 256 + 128 + d] += vs / (float)k;
}

// ---------------- final MLP ----------------
__global__ __launch_bounds__(256) void mlp1(const float* __restrict__ h, const float* __restrict__ W1,
    const float* __restrict__ b1, float* __restrict__ h1) {
  int o = blockIdx.x * 256 + threadIdx.x;  // 64*128
  int g = o >> 7, j = o & 127;
  const float* hp = h + g * 256;
  const float* wp = W1 + j * 256;
  float a = b1[j];
  for (int c = 0; c < 256; ++c) a += hp[c] * wp[c];
  h1[o] = fmaxf(a, 0.f);
}

__global__ __launch_bounds__(256) void mlp2(const float* __restrict__ h1, const float* __restrict__ W2,
    const float* __restrict__ b2, float* __restrict__ h2) {
  int o = blockIdx.x * 256 + threadIdx.x;  // 64*64
  int g = o >> 6, j = o & 63;
  const float* hp = h1 + g * 128;
  const float* wp = W2 + j * 128;
  float a = b2[j];
  for (int c = 0; c < 128; ++c) a += hp[c] * wp[c];
  h2[o] = fmaxf(a, 0.f);
}

__global__ __launch_bounds__(64) void mlp3(const float* __restrict__ h2, const float* __restrict__ W3,
    const float* __restrict__ b3, float* __restrict__ out) {
  int g = threadIdx.x;
  if (g >= 64) return;
  const float* hp = h2 + g * 64;
  float a = b3[0];
  for (int c = 0; c < 64; ++c) a += hp[c] * W3[c];
  out[g] = 1.f / (1.f + expf(-a));
}

extern "C" void kernel_launch(void* const* d_in, const int* in_sizes, int n_in,
                              void* d_out, int out_size, void* d_ws, size_t ws_size,
                              hipStream_t stream) {
  const int* node_ids = (const int*)d_in[0];
  const int* ei = (const int*)d_in[1];
  const float* emb = (const float*)d_in[3];
  const float* W[3][4] = {
      {(const float*)d_in[4], (const float*)d_in[5], (const float*)d_in[6], (const float*)d_in[7]},
      {(const float*)d_in[8], (const float*)d_in[9], (const float*)d_in[10], (const float*)d_in[11]},
      {(const float*)d_in[12], (const float*)d_in[13], (const float*)d_in[14], (const float*)d_in[15]}};
  const float* W1 = (const float*)d_in[16];
  const float* b1 = (const float*)d_in[17];
  const float* W2 = (const float*)d_in[18];
  const float* b2 = (const float*)d_in[19];
  const float* W3 = (const float*)d_in[20];
  const float* b3 = (const float*)d_in[21];
  float* out = (float*)d_out;

  const int E = NEDGES;
  char* ws = (char*)d_ws;
  size_t o = 0;
  auto alloc = [&](size_t bytes) { void* p = ws + o; o = (o + bytes + 255) & ~(size_t)255; return p; };
  _Float16* XH = (_Float16*)alloc((size_t)NNODES * 128 * 2);
  _Float16* MEANH = (_Float16*)alloc((size_t)NNODES * 128 * 2);
  int* ESORT = (int*)alloc((size_t)E * 4);
  int* PART = (int*)alloc((size_t)GRAPHS * NSB * 2048 * 4);
  int* CURS = (int*)alloc((size_t)GRAPHS * NSB * 2048 * 4);
  int* OFFB = (int*)alloc((size_t)NNODES * 4);
  int* DEG = (int*)alloc((size_t)NNODES * 4);
  float* SC = (float*)alloc((size_t)NNODES * 4);
  float* TS = (float*)alloc((size_t)NNODES * 4);
  int* PERM = (int*)alloc((size_t)NNODES * 4);
  int* NOOA = (int*)alloc((size_t)NNODES * 4);
  int* NOOB = (int*)alloc((size_t)NNODES * 4);
  int* ORIGA = (int*)alloc((size_t)NNODES * 4);
  int* ORIGB = (int*)alloc((size_t)NNODES * 4);
  _Float16* WH0 = (_Float16*)alloc(4096 * 8 * 2);
  _Float16* WH1 = (_Float16*)alloc(4096 * 8 * 2);
  _Float16* WH2 = (_Float16*)alloc(4096 * 8 * 2);
  float* PMAX = (float*)alloc((size_t)GRAPHS * RSLICES * 128 * 4);
  float* PSUM = (float*)alloc((size_t)GRAPHS * RSLICES * 128 * 4);
  float* H = (float*)alloc(64 * 256 * 4);
  float* H1 = (float*)alloc(64 * 128 * 4);
  float* H2 = (float*)alloc(64 * 64 * 4);

  embed_kernel<<<NNODES * 16 / 256, 256, 0, stream>>>(node_ids, emb, XH);
  hipMemsetAsync(H, 0, 64 * 256 * 4, stream);
  convert_w<<<16, 256, 0, stream>>>(W[0][0], W[0][1], WH0);
  convert_w<<<16, 256, 0, stream>>>(W[1][0], W[1][1], WH1);
  convert_w<<<16, 256, 0, stream>>>(W[2][0], W[2][1], WH2);

  // layer-0 CSR (built once; reused with NOO filter by layers 1/2)
  const int* src = ei;
  const int* dst = ei + E;
  csr_hist<<<GRAPHS * NSB, 1024, 0, stream>>>(src, dst, NPG, PART);
  csr_scan<<<GRAPHS, 1024, 0, stream>>>(PART, NPG, OFFB, DEG, CURS);
  csr_place<<<GRAPHS * NSB, 1024, 0, stream>>>(src, dst, NPG, CURS, ESORT);

  struct LayerP { int n, k; };                 // n = current node count; k = keep per graph
  LayerP L[3] = {{131072, 1639}, {104896, 1312}, {83968, 1050}};
  _Float16* WHs[3] = {WH0, WH1, WH2};
  int* ORIG_cur = ORIGA;   // maps current ids -> original ids (valid for li>=1)
  int* ORIG_next = ORIGB;

  for (int li = 0; li < 3; ++li) {
    int n = L[li].n, k = L[li].k;
    int np = n / 64;
    int n_new = 64 * k;
    const float *bl = W[li][2], *pw = W[li][3];

    int C = (np + 15) / 16;
    if (li == 0) {
      aggregate_kernel<<<64 * C, 256, 0, stream>>>(XH, OFFB, DEG, ESORT, MEANH, np, C);
    } else {
      aggregate_f<<<64 * C, 256, 0, stream>>>(XH, OFFB, DEG, ESORT, ORIG_cur, NOOA,
                                              MEANH, np, C);
    }
    sage_gemm<<<(n + RPB - 1) / RPB, 256, 0, stream>>>(XH, MEANH, MEANH, WHs[li], bl, pw, SC, n);
    topk_kernel<<<GRAPHS, 1024, 0, stream>>>(SC, np, k, TS, PERM, (li == 0) ? NOOA : NOOB);
    gather_kernel<<<n_new * 16 / 256, 256, 0, stream>>>(MEANH, PERM, TS, XH,
        (li == 0) ? nullptr : ORIG_cur, ORIG_next, n_new);
    { int* t = ORIG_cur; ORIG_cur = ORIG_next; ORIG_next = t; }
    readout_part<<<GRAPHS * RSLICES, 256, 0, stream>>>(XH, k, PMAX, PSUM);
    readout_comb<<<32, 256, 0, stream>>>(PMAX, PSUM, k, H);
    if (li == 1) compose_kernel<<<NNODES / 256, 256, 0, stream>>>(NOOA, NOOB, NNODES);
  }

  mlp1<<<32, 256, 0, stream>>>(H, W1, b1, H1);
  mlp2<<<16, 256, 0, stream>>>(H1, W2, b2, H2);
  mlp3<<<1, 64, 0, stream>>>(H2, W3, b3, out);
}